// Round 7
// baseline (365.485 us; speedup 1.0000x reference)
//
#include <hip/hip_runtime.h>

typedef unsigned short ushort_t;
typedef __bf16 bf16x8 __attribute__((ext_vector_type(8)));
typedef ushort_t u16x8 __attribute__((ext_vector_type(8)));
typedef float f32x4 __attribute__((ext_vector_type(4)));

#define DEVI __device__ __forceinline__

// Problem dims
constexpr int Ed = 1024;   // embed
constexpr int Hh = 16;     // heads
constexpr int Dd = 64;     // head dim
constexpr int Ss = 2048;   // seq
constexpr int Mm = 4096;   // B*S rows

DEVI float bf2f(ushort_t u) {
    union { unsigned int i; float f; } v; v.i = ((unsigned int)u) << 16; return v.f;
}
DEVI ushort_t f2bf(float f) {
    union { float f; unsigned int i; } v; v.f = f;
    unsigned int r = v.i + 0x7fffu + ((v.i >> 16) & 1u);  // RNE
    return (ushort_t)(r >> 16);
}

// ---------------- NT GEMM core: C[m,n] = sum_k A[m,k]*W[n,k] ----------------
// fp32 inputs, converted to bf16 during LDS staging.
// 128x128 tile, BK=64, 256 threads (4 waves in 2x2), 16x16x32 bf16 MFMA.
DEVI void gemm_core_f32(const float* __restrict__ A, const float* __restrict__ W,
                        ushort_t* As, ushort_t* Bs, int tm, int tn, int K,
                        f32x4 acc[4][4])
{
    const int tid  = threadIdx.x;
    const int w    = tid >> 6;
    const int lane = tid & 63;
    const int quad = lane >> 4;
    const int l15  = lane & 15;
    const int wy   = w >> 1, wx = w & 1;

    for (int k0 = 0; k0 < K; k0 += 64) {
        __syncthreads();
#pragma unroll
        for (int i = 0; i < 8; ++i) {
            int e4  = tid + i * 256;     // 2048 float4 units per 128x64 tile
            int row = e4 >> 4;           // 16 float4 per row
            int c4  = (e4 & 15) * 4;
            float4 va = *(const float4*)&A[(size_t)(tm + row) * K + k0 + c4];
            float4 vb = *(const float4*)&W[(size_t)(tn + row) * K + k0 + c4];
            ushort4 ua; ua.x = f2bf(va.x); ua.y = f2bf(va.y); ua.z = f2bf(va.z); ua.w = f2bf(va.w);
            ushort4 ub; ub.x = f2bf(vb.x); ub.y = f2bf(vb.y); ub.z = f2bf(vb.z); ub.w = f2bf(vb.w);
            *(ushort4*)&As[row * 64 + c4] = ua;
            *(ushort4*)&Bs[row * 64 + c4] = ub;
        }
        __syncthreads();
#pragma unroll
        for (int ks = 0; ks < 64; ks += 32) {
            bf16x8 a[4], b[4];
#pragma unroll
            for (int mi = 0; mi < 4; ++mi)
                a[mi] = *(const bf16x8*)&As[(wy * 64 + mi * 16 + l15) * 64 + ks + quad * 8];
#pragma unroll
            for (int ni = 0; ni < 4; ++ni)
                b[ni] = *(const bf16x8*)&Bs[(wx * 64 + ni * 16 + l15) * 64 + ks + quad * 8];
#pragma unroll
            for (int mi = 0; mi < 4; ++mi)
#pragma unroll
                for (int ni = 0; ni < 4; ++ni)
                    acc[mi][ni] = __builtin_amdgcn_mfma_f32_16x16x32_bf16(
                        a[mi], b[ni], acc[mi][ni], 0, 0, 0);
        }
    }
}

// Fused QKV projection. z-dim selects {Q,K,V}. Q,K stored [B,H,S,D]; V stored [B,H,D,S].
__global__ __launch_bounds__(256, 2) void qkv_gemm(
    const float* __restrict__ x,
    const float* __restrict__ Wq, const float* __restrict__ bq,
    const float* __restrict__ Wk, const float* __restrict__ bk,
    const float* __restrict__ Wv, const float* __restrict__ bv,
    ushort_t* __restrict__ qo, ushort_t* __restrict__ ko, ushort_t* __restrict__ vto)
{
    __shared__ __align__(16) ushort_t As[128 * 64];
    __shared__ __align__(16) ushort_t Bs[128 * 64];
    const float* W; const float* bias; ushort_t* outp; int vmode;
    if (blockIdx.z == 0)      { W = Wq; bias = bq; outp = qo;  vmode = 0; }
    else if (blockIdx.z == 1) { W = Wk; bias = bk; outp = ko;  vmode = 0; }
    else                      { W = Wv; bias = bv; outp = vto; vmode = 1; }

    const int tm = blockIdx.x * 128, tn = blockIdx.y * 128;
    f32x4 acc[4][4] = {};
    gemm_core_f32(x, W, As, Bs, tm, tn, Ed, acc);

    const int tid = threadIdx.x, w = tid >> 6, lane = tid & 63;
    const int quad = lane >> 4, l15 = lane & 15;
    const int wy = w >> 1, wx = w & 1;
#pragma unroll
    for (int ni = 0; ni < 4; ++ni) {
        int gc = tn + wx * 64 + ni * 16 + l15;
        float bb = bias[gc];
        int h = gc >> 6, d = gc & 63;
#pragma unroll
        for (int mi = 0; mi < 4; ++mi) {
#pragma unroll
            for (int r = 0; r < 4; ++r) {
                int gr = tm + wy * 64 + mi * 16 + quad * 4 + r;
                int b_ = gr >> 11, s_ = gr & 2047;
                float v = acc[mi][ni][r] + bb;
                size_t addr;
                if (vmode == 0) addr = ((size_t)(b_ * Hh + h) * Ss + s_) * Dd + d;
                else            addr = ((size_t)(b_ * Hh + h) * Dd + d) * Ss + s_;
                outp[addr] = f2bf(v);
            }
        }
    }
}

// ---------------- mixed NT GEMM core (A bf16, W fp32) ----------------------
DEVI void gemm_core_mixed(const ushort_t* __restrict__ A, const float* __restrict__ W,
                          ushort_t* As, ushort_t* Bs, int tm, int tn, int K,
                          f32x4 acc[4][4])
{
    const int tid  = threadIdx.x;
    const int w    = tid >> 6;
    const int lane = tid & 63;
    const int quad = lane >> 4;
    const int l15  = lane & 15;
    const int wy   = w >> 1, wx = w & 1;

    for (int k0 = 0; k0 < K; k0 += 64) {
        __syncthreads();
#pragma unroll
        for (int i = 0; i < 4; ++i) {    // A tile: 1024 u16x8 slots
            int e8  = tid + i * 256;
            int row = e8 >> 3;
            int c8  = (e8 & 7) * 8;
            u16x8 va = *(const u16x8*)&A[(size_t)(tm + row) * K + k0 + c8];
            *(u16x8*)&As[row * 64 + c8] = va;
        }
#pragma unroll
        for (int i = 0; i < 8; ++i) {    // W tile: fp32 -> bf16
            int e4  = tid + i * 256;
            int row = e4 >> 4;
            int c4  = (e4 & 15) * 4;
            float4 vb = *(const float4*)&W[(size_t)(tn + row) * K + k0 + c4];
            ushort4 ub; ub.x = f2bf(vb.x); ub.y = f2bf(vb.y); ub.z = f2bf(vb.z); ub.w = f2bf(vb.w);
            *(ushort4*)&Bs[row * 64 + c4] = ub;
        }
        __syncthreads();
#pragma unroll
        for (int ks = 0; ks < 64; ks += 32) {
            bf16x8 a[4], b[4];
#pragma unroll
            for (int mi = 0; mi < 4; ++mi)
                a[mi] = *(const bf16x8*)&As[(wy * 64 + mi * 16 + l15) * 64 + ks + quad * 8];
#pragma unroll
            for (int ni = 0; ni < 4; ++ni)
                b[ni] = *(const bf16x8*)&Bs[(wx * 64 + ni * 16 + l15) * 64 + ks + quad * 8];
#pragma unroll
            for (int mi = 0; mi < 4; ++mi)
#pragma unroll
                for (int ni = 0; ni < 4; ++ni)
                    acc[mi][ni] = __builtin_amdgcn_mfma_f32_16x16x32_bf16(
                        a[mi], b[ni], acc[mi][ni], 0, 0, 0);
        }
    }
}

// Output projection: out = ctx @ Wo^T + bo, row-major [M,E] FP32 output.
__global__ __launch_bounds__(256, 2) void out_gemm(
    const ushort_t* __restrict__ ctx, const float* __restrict__ Wo,
    const float* __restrict__ bo, float* __restrict__ out)
{
    __shared__ __align__(16) ushort_t As[128 * 64];
    __shared__ __align__(16) ushort_t Bs[128 * 64];
    const int tm = blockIdx.x * 128, tn = blockIdx.y * 128;
    f32x4 acc[4][4] = {};
    gemm_core_mixed(ctx, Wo, As, Bs, tm, tn, Ed, acc);

    const int tid = threadIdx.x, w = tid >> 6, lane = tid & 63;
    const int quad = lane >> 4, l15 = lane & 15;
    const int wy = w >> 1, wx = w & 1;
#pragma unroll
    for (int ni = 0; ni < 4; ++ni) {
        int gc = tn + wx * 64 + ni * 16 + l15;
        float bb = bo[gc];
#pragma unroll
        for (int mi = 0; mi < 4; ++mi)
#pragma unroll
            for (int r = 0; r < 4; ++r) {
                int gr = tm + wy * 64 + mi * 16 + quad * 4 + r;
                out[(size_t)gr * Ed + gc] = acc[mi][ni][r] + bb;   // fp32 store
            }
    }
}

// Flash-style attention. grid = (S/128, B*H). 128 Q-rows per block, 4 waves x 32 rows.
// Q,K: [B,H,S,D]; Vt: [B,H,D,S]; ctx out: [B,S,E] bf16.
__global__ __launch_bounds__(256, 2) void attn(
    const ushort_t* __restrict__ Q, const ushort_t* __restrict__ Kk,
    const ushort_t* __restrict__ Vt, const float* __restrict__ z,
    ushort_t* __restrict__ ctx)
{
    __shared__ __align__(16) ushort_t Qs[128 * 64];
    __shared__ __align__(16) ushort_t Ks[64 * 64];
    __shared__ __align__(16) ushort_t Vs[64 * 64];     // [d][s] (V transposed)
    __shared__ __align__(16) ushort_t Ps[4][32 * 64];  // per-wave P scratch

    const int tid = threadIdx.x, w = tid >> 6, lane = tid & 63;
    const int quad = lane >> 4, l15 = lane & 15;
    const int qt = blockIdx.x;           // Q tile (0..15)
    const int bh = blockIdx.y;           // 0..31
    const int h = bh & (Hh - 1), b_ = bh >> 4;
    const size_t base = (size_t)bh * Ss * Dd;

    const float gate  = 1.f / (1.f + __expf(-z[h]));
    const float scale = gate * 0.125f;   // gate / sqrt(64)

    // stage Q tile [128][64]
#pragma unroll
    for (int i = 0; i < 4; ++i) {
        int e8  = tid + i * 256;         // 1024 slots of 8 ushorts
        int row = e8 >> 3;
        int c8  = (e8 & 7) * 8;
        u16x8 v = *(const u16x8*)&Q[base + (size_t)(qt * 128 + row) * Dd + c8];
        *(u16x8*)&Qs[row * 64 + c8] = v;
    }
    __syncthreads();

    bf16x8 aQ[2][2];
#pragma unroll
    for (int mi = 0; mi < 2; ++mi)
#pragma unroll
        for (int c = 0; c < 2; ++c)
            aQ[mi][c] = *(const bf16x8*)&Qs[(w * 32 + mi * 16 + l15) * 64 + c * 32 + quad * 8];

    f32x4 accO[2][4] = {};
    float mrow[2][4], lrow[2][4];
#pragma unroll
    for (int mi = 0; mi < 2; ++mi)
#pragma unroll
        for (int r = 0; r < 4; ++r) { mrow[mi][r] = -1e30f; lrow[mi][r] = 0.f; }

    for (int kt = 0; kt < Ss / 64; ++kt) {
        __syncthreads();   // protect K/V LDS from previous iteration's readers
#pragma unroll
        for (int i = 0; i < 2; ++i) {
            int e8  = tid + i * 256;     // 512 slots per 64x64 tile
            int row = e8 >> 3;           // 0..63
            int c8  = (e8 & 7) * 8;
            u16x8 vk = *(const u16x8*)&Kk[base + (size_t)(kt * 64 + row) * Dd + c8];
            u16x8 vv = *(const u16x8*)&Vt[base + (size_t)row * Ss + kt * 64 + c8];
            *(u16x8*)&Ks[row * 64 + c8] = vk;
            *(u16x8*)&Vs[row * 64 + c8] = vv;
        }
        __syncthreads();

        // S = Q K^T  (per wave: 32 q-rows x 64 k-cols)
        f32x4 sAcc[2][4] = {};
        bf16x8 bK[4][2];
#pragma unroll
        for (int ni = 0; ni < 4; ++ni)
#pragma unroll
            for (int c = 0; c < 2; ++c)
                bK[ni][c] = *(const bf16x8*)&Ks[(ni * 16 + l15) * 64 + c * 32 + quad * 8];
#pragma unroll
        for (int mi = 0; mi < 2; ++mi)
#pragma unroll
            for (int ni = 0; ni < 4; ++ni)
#pragma unroll
                for (int c = 0; c < 2; ++c)
                    sAcc[mi][ni] = __builtin_amdgcn_mfma_f32_16x16x32_bf16(
                        aQ[mi][c], bK[ni][c], sAcc[mi][ni], 0, 0, 0);

        // online softmax (rows live on lanes sharing quad; reduce over low 4 lane bits)
#pragma unroll
        for (int mi = 0; mi < 2; ++mi) {
            float sc[4][4];
#pragma unroll
            for (int ni = 0; ni < 4; ++ni)
#pragma unroll
                for (int r = 0; r < 4; ++r) sc[ni][r] = sAcc[mi][ni][r] * scale;
#pragma unroll
            for (int r = 0; r < 4; ++r) {
                float mx = fmaxf(fmaxf(sc[0][r], sc[1][r]), fmaxf(sc[2][r], sc[3][r]));
                mx = fmaxf(mx, __shfl_xor(mx, 1));
                mx = fmaxf(mx, __shfl_xor(mx, 2));
                mx = fmaxf(mx, __shfl_xor(mx, 4));
                mx = fmaxf(mx, __shfl_xor(mx, 8));
                float mnew = fmaxf(mrow[mi][r], mx);
                float alpha = __expf(mrow[mi][r] - mnew);
                float rsum = 0.f;
#pragma unroll
                for (int ni = 0; ni < 4; ++ni) {
                    float p = __expf(sc[ni][r] - mnew);
                    sc[ni][r] = p;
                    rsum += p;
                }
                rsum += __shfl_xor(rsum, 1);
                rsum += __shfl_xor(rsum, 2);
                rsum += __shfl_xor(rsum, 4);
                rsum += __shfl_xor(rsum, 8);
                lrow[mi][r] = lrow[mi][r] * alpha + rsum;
                mrow[mi][r] = mnew;
#pragma unroll
                for (int ni = 0; ni < 4; ++ni) accO[mi][ni][r] *= alpha;
#pragma unroll
                for (int ni = 0; ni < 4; ++ni)
                    Ps[w][(mi * 16 + quad * 4 + r) * 64 + ni * 16 + l15] = f2bf(sc[ni][r]);
            }
        }
        __syncthreads();   // P visible

        // O += P V   (A = P from LDS, B = Vt rows, k = 64 key cols)
#pragma unroll
        for (int c = 0; c < 2; ++c) {
            bf16x8 bV[4];
#pragma unroll
            for (int ni = 0; ni < 4; ++ni)
                bV[ni] = *(const bf16x8*)&Vs[(ni * 16 + l15) * 64 + c * 32 + quad * 8];
#pragma unroll
            for (int mi = 0; mi < 2; ++mi) {
                bf16x8 aP = *(const bf16x8*)&Ps[w][(mi * 16 + l15) * 64 + c * 32 + quad * 8];
#pragma unroll
                for (int ni = 0; ni < 4; ++ni)
                    accO[mi][ni] = __builtin_amdgcn_mfma_f32_16x16x32_bf16(
                        aP, bV[ni], accO[mi][ni], 0, 0, 0);
            }
        }
    }

    // epilogue: ctx[b, s, h*64+d] = O / l  (bf16 intermediate)
#pragma unroll
    for (int mi = 0; mi < 2; ++mi)
#pragma unroll
        for (int r = 0; r < 4; ++r) {
            int srow = qt * 128 + w * 32 + mi * 16 + quad * 4 + r;
            float inv = 1.f / lrow[mi][r];
#pragma unroll
            for (int ni = 0; ni < 4; ++ni) {
                int d = ni * 16 + l15;
                ctx[((size_t)(b_ * Ss + srow)) * Ed + h * Dd + d] =
                    f2bf(accO[mi][ni][r] * inv);
            }
        }
}

__global__ void penalty_k(const float* __restrict__ z, float* __restrict__ out) {
    if (threadIdx.x == 0) {
        float s = 0.f;
        for (int h = 0; h < Hh; ++h) s += 1.f / (1.f + __expf(-z[h]));
        out[(size_t)Mm * Ed] = s * 0.01f;   // fp32 store
    }
}

extern "C" void kernel_launch(void* const* d_in, const int* in_sizes, int n_in,
                              void* d_out, int out_size, void* d_ws, size_t ws_size,
                              hipStream_t stream) {
    const float* x  = (const float*)d_in[0];
    const float* Wq = (const float*)d_in[1];
    const float* bq = (const float*)d_in[2];
    const float* Wk = (const float*)d_in[3];
    const float* bk = (const float*)d_in[4];
    const float* Wv = (const float*)d_in[5];
    const float* bv = (const float*)d_in[6];
    const float* Wo = (const float*)d_in[7];
    const float* bo = (const float*)d_in[8];
    const float* z  = (const float*)d_in[9];
    float* out = (float*)d_out;                   // FP32 output (reference dtype)

    // workspace layout (ushort elements) — 32 MB total
    ushort_t* qw = (ushort_t*)d_ws;               // [B,H,S,D] 8 MB
    ushort_t* kw = qw + (size_t)Mm * Ed;          // [B,H,S,D] 8 MB
    ushort_t* vT = kw + (size_t)Mm * Ed;          // [B,H,D,S] 8 MB
    ushort_t* cx = vT + (size_t)Mm * Ed;          // [B,S,E]   8 MB

    dim3 blk(256);
    qkv_gemm<<<dim3(Mm / 128, Ed / 128, 3), blk, 0, stream>>>(
        x, Wq, bq, Wk, bk, Wv, bv, qw, kw, vT);
    attn<<<dim3(Ss / 128, 2 * Hh), blk, 0, stream>>>(qw, kw, vT, z, cx);
    out_gemm<<<dim3(Mm / 128, Ed / 128), blk, 0, stream>>>(cx, Wo, bo, out);
    penalty_k<<<1, 64, 0, stream>>>(z, out);
}

// Round 8
// 284.034 us; speedup vs baseline: 1.2868x; 1.2868x over previous
//
#include <hip/hip_runtime.h>

typedef unsigned short ushort_t;
typedef __bf16 bf16x8 __attribute__((ext_vector_type(8)));
typedef ushort_t u16x8 __attribute__((ext_vector_type(8)));
typedef float f32x4 __attribute__((ext_vector_type(4)));

#define DEVI __device__ __forceinline__

// Problem dims
constexpr int Ed = 1024;   // embed
constexpr int Hh = 16;     // heads
constexpr int Dd = 64;     // head dim
constexpr int Ss = 2048;   // seq
constexpr int Mm = 4096;   // B*S rows

constexpr int NX4 = Mm * Ed / 4;   // 1048576 float4 in x
constexpr int NW4 = Ed * Ed / 4;   // 262144 float4 per weight

DEVI ushort_t f2bf(float f) {
    union { float f; unsigned int i; } v; v.f = f;
    unsigned int r = v.i + 0x7fffu + ((v.i >> 16) & 1u);  // RNE
    return (ushort_t)(r >> 16);
}

// One-shot fp32 -> bf16 conversion of x + 4 weight matrices.
__global__ __launch_bounds__(256) void cvt_all(
    const float* __restrict__ x,  const float* __restrict__ Wq,
    const float* __restrict__ Wk, const float* __restrict__ Wv,
    const float* __restrict__ Wo,
    ushort_t* __restrict__ xb,  ushort_t* __restrict__ Wqb,
    ushort_t* __restrict__ Wkb, ushort_t* __restrict__ Wvb,
    ushort_t* __restrict__ Wob)
{
    int i = blockIdx.x * 256 + threadIdx.x;
    const float* s; ushort_t* d; int off;
    if (i < NX4)                { s = x;  d = xb;  off = i; }
    else if (i < NX4 + NW4)     { s = Wq; d = Wqb; off = i - NX4; }
    else if (i < NX4 + 2 * NW4) { s = Wk; d = Wkb; off = i - NX4 - NW4; }
    else if (i < NX4 + 3 * NW4) { s = Wv; d = Wvb; off = i - NX4 - 2 * NW4; }
    else                        { s = Wo; d = Wob; off = i - NX4 - 3 * NW4; }
    float4 v = ((const float4*)s)[off];
    ushort4 o; o.x = f2bf(v.x); o.y = f2bf(v.y); o.z = f2bf(v.z); o.w = f2bf(v.w);
    ((ushort4*)d)[off] = o;
}

// async global->LDS, 16B per lane; LDS dest = uniform base + lane*16
DEVI void gld16(const void* g, void* l) {
    __builtin_amdgcn_global_load_lds(
        (__attribute__((address_space(1))) void*)(g),
        (__attribute__((address_space(3))) void*)(l), 16, 0, 0);
}

// ---------------- NT GEMM core: C[m,n] = sum_k A[m,k]*W[n,k] ----------------
// bf16 inputs, global_load_lds width-16 staging (m97 pattern).
// 128x128 tile, BK=64, 256 threads (4 waves in 2x2), 16x16x32 bf16 MFMA.
DEVI void gemm_core(const ushort_t* __restrict__ A, const ushort_t* __restrict__ W,
                    ushort_t* As, ushort_t* Bs, int tm, int tn, int K,
                    f32x4 acc[4][4])
{
    const int tid  = threadIdx.x;
    const int w    = tid >> 6;
    const int lane = tid & 63;
    const int quad = lane >> 4;
    const int l15  = lane & 15;
    const int wy   = w >> 1, wx = w & 1;
    const int rowc = lane >> 3;          // row within 8-row chunk
    const int col8 = (lane & 7) * 8;     // element col (16B granules)

    for (int k0 = 0; k0 < K; k0 += 64) {
        __syncthreads();                 // protect LDS from previous iter's readers
#pragma unroll
        for (int i = 0; i < 4; ++i) {
            int chunk = w * 4 + i;       // 16 chunks of 1024B each per tile
            int row = chunk * 8 + rowc;
            gld16(A + (size_t)(tm + row) * K + k0 + col8, (char*)As + chunk * 1024);
            gld16(W + (size_t)(tn + row) * K + k0 + col8, (char*)Bs + chunk * 1024);
        }
        __syncthreads();                 // staging complete
#pragma unroll
        for (int ks = 0; ks < 64; ks += 32) {
            bf16x8 a[4], b[4];
#pragma unroll
            for (int mi = 0; mi < 4; ++mi)
                a[mi] = *(const bf16x8*)&As[(wy * 64 + mi * 16 + l15) * 64 + ks + quad * 8];
#pragma unroll
            for (int ni = 0; ni < 4; ++ni)
                b[ni] = *(const bf16x8*)&Bs[(wx * 64 + ni * 16 + l15) * 64 + ks + quad * 8];
#pragma unroll
            for (int mi = 0; mi < 4; ++mi)
#pragma unroll
                for (int ni = 0; ni < 4; ++ni)
                    acc[mi][ni] = __builtin_amdgcn_mfma_f32_16x16x32_bf16(
                        a[mi], b[ni], acc[mi][ni], 0, 0, 0);
        }
    }
}

// Fused QKV projection. z selects {Q,K,V}. Q,K stored [B,H,S,D]; V stored [B,H,D,S].
__global__ __launch_bounds__(256, 2) void qkv_gemm(
    const ushort_t* __restrict__ x,
    const ushort_t* __restrict__ Wq, const float* __restrict__ bq,
    const ushort_t* __restrict__ Wk, const float* __restrict__ bk,
    const ushort_t* __restrict__ Wv, const float* __restrict__ bv,
    ushort_t* __restrict__ qo, ushort_t* __restrict__ ko, ushort_t* __restrict__ vto)
{
    __shared__ __align__(16) ushort_t As[128 * 64];
    __shared__ __align__(16) ushort_t Bs[128 * 64];
    const ushort_t* W; const float* bias; ushort_t* outp; int vmode;
    if (blockIdx.z == 0)      { W = Wq; bias = bq; outp = qo;  vmode = 0; }
    else if (blockIdx.z == 1) { W = Wk; bias = bk; outp = ko;  vmode = 0; }
    else                      { W = Wv; bias = bv; outp = vto; vmode = 1; }

    const int tm = blockIdx.x * 128, tn = blockIdx.y * 128;
    f32x4 acc[4][4] = {};
    gemm_core(x, W, As, Bs, tm, tn, Ed, acc);

    const int tid = threadIdx.x, w = tid >> 6, lane = tid & 63;
    const int quad = lane >> 4, l15 = lane & 15;
    const int wy = w >> 1, wx = w & 1;
#pragma unroll
    for (int ni = 0; ni < 4; ++ni) {
        int gc = tn + wx * 64 + ni * 16 + l15;
        float bb = bias[gc];
        int h = gc >> 6, d = gc & 63;
#pragma unroll
        for (int mi = 0; mi < 4; ++mi) {
#pragma unroll
            for (int r = 0; r < 4; ++r) {
                int gr = tm + wy * 64 + mi * 16 + quad * 4 + r;
                int b_ = gr >> 11, s_ = gr & 2047;
                float v = acc[mi][ni][r] + bb;
                size_t addr;
                if (vmode == 0) addr = ((size_t)(b_ * Hh + h) * Ss + s_) * Dd + d;
                else            addr = ((size_t)(b_ * Hh + h) * Dd + d) * Ss + s_;
                outp[addr] = f2bf(v);
            }
        }
    }
}

// Output projection: out = ctx @ Wo^T + bo, row-major [M,E] FP32 output.
__global__ __launch_bounds__(256, 2) void out_gemm(
    const ushort_t* __restrict__ ctx, const ushort_t* __restrict__ Wo,
    const float* __restrict__ bo, float* __restrict__ out)
{
    __shared__ __align__(16) ushort_t As[128 * 64];
    __shared__ __align__(16) ushort_t Bs[128 * 64];
    const int tm = blockIdx.x * 128, tn = blockIdx.y * 128;
    f32x4 acc[4][4] = {};
    gemm_core(ctx, Wo, As, Bs, tm, tn, Ed, acc);

    const int tid = threadIdx.x, w = tid >> 6, lane = tid & 63;
    const int quad = lane >> 4, l15 = lane & 15;
    const int wy = w >> 1, wx = w & 1;
#pragma unroll
    for (int ni = 0; ni < 4; ++ni) {
        int gc = tn + wx * 64 + ni * 16 + l15;
        float bb = bo[gc];
#pragma unroll
        for (int mi = 0; mi < 4; ++mi)
#pragma unroll
            for (int r = 0; r < 4; ++r) {
                int gr = tm + wy * 64 + mi * 16 + quad * 4 + r;
                out[(size_t)gr * Ed + gc] = acc[mi][ni][r] + bb;   // fp32 store
            }
    }
}

// Flash attention, 64 Q-rows/block, 4 waves x 16 rows. grid = (S/64, B*H).
// Q,K: [B,H,S,D]; Vt: [B,H,D,S]; ctx out: [B,S,E] bf16.
// LDS padded (stride 68 / 66) to kill bank conflicts; 2 barriers per K-tile.
__global__ __launch_bounds__(256, 4) void attn(
    const ushort_t* __restrict__ Q, const ushort_t* __restrict__ Kk,
    const ushort_t* __restrict__ Vt, const float* __restrict__ z,
    ushort_t* __restrict__ ctx)
{
    __shared__ __align__(16) ushort_t Qs[64 * 68];
    __shared__ __align__(16) ushort_t Ks[64 * 68];     // [key][d]
    __shared__ __align__(16) ushort_t Vs[64 * 68];     // [d][key] (V transposed)
    __shared__ __align__(16) ushort_t Ps[4][16 * 66];  // per-wave P scratch

    const int tid = threadIdx.x, w = tid >> 6, lane = tid & 63;
    const int quad = lane >> 4, l15 = lane & 15;
    const int qt = blockIdx.x;           // 0..31
    const int bh = blockIdx.y;           // 0..31
    const int h = bh & (Hh - 1), b_ = bh >> 4;
    const size_t base = (size_t)bh * Ss * Dd;

    const float gate  = 1.f / (1.f + __expf(-z[h]));
    const float scale = gate * 0.125f;   // gate / sqrt(64)

    // stage Q tile [64][64] -> padded stride 68
#pragma unroll
    for (int i = 0; i < 2; ++i) {
        int e8  = tid + i * 256;         // 512 slots of 8 ushorts
        int row = e8 >> 3;
        int c8  = (e8 & 7) * 8;
        *(u16x8*)&Qs[row * 68 + c8] =
            *(const u16x8*)&Q[base + (size_t)(qt * 64 + row) * Dd + c8];
    }
    __syncthreads();

    bf16x8 aQ[2];
#pragma unroll
    for (int c = 0; c < 2; ++c)
        aQ[c] = *(const bf16x8*)&Qs[(w * 16 + l15) * 68 + c * 32 + quad * 8];

    f32x4 accO[4] = {};
    float mrow[4], lrow[4];
#pragma unroll
    for (int r = 0; r < 4; ++r) { mrow[r] = -1e30f; lrow[r] = 0.f; }

    for (int kt = 0; kt < Ss / 64; ++kt) {
        __syncthreads();   // protect K/V LDS from previous iteration's readers
#pragma unroll
        for (int i = 0; i < 2; ++i) {
            int e8  = tid + i * 256;     // 512 slots per 64x64 tile
            int row = e8 >> 3;           // 0..63
            int c8  = (e8 & 7) * 8;
            *(u16x8*)&Ks[row * 68 + c8] =
                *(const u16x8*)&Kk[base + (size_t)(kt * 64 + row) * Dd + c8];
            *(u16x8*)&Vs[row * 68 + c8] =
                *(const u16x8*)&Vt[base + (size_t)row * Ss + kt * 64 + c8];
        }
        __syncthreads();

        // S = Q K^T  (per wave: 16 q-rows x 64 k-cols)
        f32x4 sAcc[4] = {};
#pragma unroll
        for (int ni = 0; ni < 4; ++ni) {
            bf16x8 b0 = *(const bf16x8*)&Ks[(ni * 16 + l15) * 68 + quad * 8];
            bf16x8 b1 = *(const bf16x8*)&Ks[(ni * 16 + l15) * 68 + 32 + quad * 8];
            sAcc[ni] = __builtin_amdgcn_mfma_f32_16x16x32_bf16(aQ[0], b0, sAcc[ni], 0, 0, 0);
            sAcc[ni] = __builtin_amdgcn_mfma_f32_16x16x32_bf16(aQ[1], b1, sAcc[ni], 0, 0, 0);
        }

        // online softmax (row = quad*4+r; reduce over l15's 4 lane bits)
#pragma unroll
        for (int ni = 0; ni < 4; ++ni)
#pragma unroll
            for (int r = 0; r < 4; ++r) sAcc[ni][r] *= scale;
#pragma unroll
        for (int r = 0; r < 4; ++r) {
            float mx = fmaxf(fmaxf(sAcc[0][r], sAcc[1][r]), fmaxf(sAcc[2][r], sAcc[3][r]));
            mx = fmaxf(mx, __shfl_xor(mx, 1));
            mx = fmaxf(mx, __shfl_xor(mx, 2));
            mx = fmaxf(mx, __shfl_xor(mx, 4));
            mx = fmaxf(mx, __shfl_xor(mx, 8));
            float mnew  = fmaxf(mrow[r], mx);
            float alpha = __expf(mrow[r] - mnew);
            float rsum = 0.f;
#pragma unroll
            for (int ni = 0; ni < 4; ++ni) {
                float p = __expf(sAcc[ni][r] - mnew);
                Ps[w][(quad * 4 + r) * 66 + ni * 16 + l15] = f2bf(p);
                rsum += p;
            }
            rsum += __shfl_xor(rsum, 1);
            rsum += __shfl_xor(rsum, 2);
            rsum += __shfl_xor(rsum, 4);
            rsum += __shfl_xor(rsum, 8);
            lrow[r] = lrow[r] * alpha + rsum;
            mrow[r] = mnew;
#pragma unroll
            for (int ni = 0; ni < 4; ++ni) accO[ni][r] *= alpha;
        }
        // NO barrier: Ps is per-wave; intra-wave LDS ordering via lgkmcnt.

        // O += P V   (A = P from LDS, B = Vt rows, k = 64 key cols)
#pragma unroll
        for (int c = 0; c < 2; ++c) {
            bf16x8 aP = *(const bf16x8*)&Ps[w][l15 * 66 + c * 32 + quad * 8];
#pragma unroll
            for (int ni = 0; ni < 4; ++ni) {
                bf16x8 bV = *(const bf16x8*)&Vs[(ni * 16 + l15) * 68 + c * 32 + quad * 8];
                accO[ni] = __builtin_amdgcn_mfma_f32_16x16x32_bf16(aP, bV, accO[ni], 0, 0, 0);
            }
        }
    }

    // epilogue: ctx[b, s, h*64+d] = O / l  (bf16 intermediate)
#pragma unroll
    for (int r = 0; r < 4; ++r) {
        int srow = qt * 64 + w * 16 + quad * 4 + r;
        float inv = 1.f / lrow[r];
#pragma unroll
        for (int ni = 0; ni < 4; ++ni) {
            int d = ni * 16 + l15;
            ctx[((size_t)(b_ * Ss + srow)) * Ed + h * Dd + d] = f2bf(accO[ni][r] * inv);
        }
    }
}

__global__ void penalty_k(const float* __restrict__ z, float* __restrict__ out) {
    if (threadIdx.x == 0) {
        float s = 0.f;
        for (int h = 0; h < Hh; ++h) s += 1.f / (1.f + __expf(-z[h]));
        out[(size_t)Mm * Ed] = s * 0.01f;   // fp32 store
    }
}

extern "C" void kernel_launch(void* const* d_in, const int* in_sizes, int n_in,
                              void* d_out, int out_size, void* d_ws, size_t ws_size,
                              hipStream_t stream) {
    const float* x  = (const float*)d_in[0];
    const float* Wq = (const float*)d_in[1];
    const float* bq = (const float*)d_in[2];
    const float* Wk = (const float*)d_in[3];
    const float* bk = (const float*)d_in[4];
    const float* Wv = (const float*)d_in[5];
    const float* bv = (const float*)d_in[6];
    const float* Wo = (const float*)d_in[7];
    const float* bo = (const float*)d_in[8];
    const float* z  = (const float*)d_in[9];
    float* out = (float*)d_out;                   // FP32 output

    // workspace layout (ushort elements) — 48 MB total (R2-proven size)
    ushort_t* xb  = (ushort_t*)d_ws;              // [M,E]     8 MB
    ushort_t* Wqb = xb  + (size_t)Mm * Ed;        // [E,E]     2 MB
    ushort_t* Wkb = Wqb + (size_t)Ed * Ed;
    ushort_t* Wvb = Wkb + (size_t)Ed * Ed;
    ushort_t* Wob = Wvb + (size_t)Ed * Ed;
    ushort_t* qw  = Wob + (size_t)Ed * Ed;        // [B,H,S,D] 8 MB
    ushort_t* kw  = qw + (size_t)Mm * Ed;         // [B,H,S,D] 8 MB
    ushort_t* vT  = kw + (size_t)Mm * Ed;         // [B,H,D,S] 8 MB
    ushort_t* cx  = vT + (size_t)Mm * Ed;         // [B,S,E]   8 MB

    dim3 blk(256);
    cvt_all<<<dim3((NX4 + 4 * NW4) / 256), blk, 0, stream>>>(
        x, Wq, Wk, Wv, Wo, xb, Wqb, Wkb, Wvb, Wob);
    qkv_gemm<<<dim3(Mm / 128, Ed / 128, 3), blk, 0, stream>>>(
        xb, Wqb, bq, Wkb, bk, Wvb, bv, qw, kw, vT);
    attn<<<dim3(Ss / 64, 2 * Hh), blk, 0, stream>>>(qw, kw, vT, z, cx);
    out_gemm<<<dim3(Mm / 128, Ed / 128), blk, 0, stream>>>(cx, Wob, bo, out);
    penalty_k<<<1, 64, 0, stream>>>(z, out);
}